// Round 6
// baseline (1606.641 us; speedup 1.0000x reference)
//
#include <hip/hip_runtime.h>
#include <hip/hip_fp16.h>
#include <math.h>

#define N_NODES 100000
#define N_PAD   100352   // 98 * 1024, for the scan kernels
#define N_EDGES 1600000
#define N_REL   3
#define F_DIM   128
#define H_DIM   64
#define O_DIM   32
#define B_NODES 50000
#define BN_EPS  1e-5f

// ---------------------------------------------------------------- degree (int)
__global__ __launch_bounds__(256) void k_deg(const int* __restrict__ dst,
                                             int* __restrict__ deg) {
    int e = blockIdx.x * 256 + threadIdx.x;
    if (e < N_EDGES) atomicAdd(&deg[dst[e]], 1);
}

__global__ __launch_bounds__(256) void k_dinv(const int* __restrict__ deg,
                                              float* __restrict__ dinv) {
    int n = blockIdx.x * 256 + threadIdx.x;
    if (n < N_NODES) dinv[n] = rsqrtf(fmaxf((float)deg[n], 1.0f));
}

// ---------------------------------------------------------------- scan phase A
__global__ __launch_bounds__(256) void k_blocksum(const int* __restrict__ deg,
                                                  int* __restrict__ blockSums) {
    const int t = threadIdx.x;
    const int4 d4 = ((const int4*)deg)[blockIdx.x * 256 + t];
    int lsum = d4.x + d4.y + d4.z + d4.w;
    __shared__ int sh[256];
    sh[t] = lsum;
    __syncthreads();
    for (int o = 128; o > 0; o >>= 1) {
        if (t < o) sh[t] += sh[t + o];
        __syncthreads();
    }
    if (t == 0) blockSums[blockIdx.x] = sh[0];
}

// ---------------------------------------------------------------- scan phase B
__global__ void k_scanoff(const int* __restrict__ blockSums,
                          int* __restrict__ blockOff,
                          int* __restrict__ rowptr, int nb) {
    __shared__ int sh[128];
    const int t = threadIdx.x;
    int v = (t < nb) ? blockSums[t] : 0;
    sh[t] = v;
    __syncthreads();
    for (int o = 1; o < 128; o <<= 1) {
        int add = (t >= o) ? sh[t - o] : 0;
        __syncthreads();
        sh[t] += add;
        __syncthreads();
    }
    if (t < nb) blockOff[t] = sh[t] - v;
    if (t == 0) rowptr[N_NODES] = N_EDGES;
}

// ---------------------------------------------------------------- scan phase C
__global__ __launch_bounds__(256) void k_scan2(const int* __restrict__ deg,
                                               const int* __restrict__ blockOff,
                                               int* __restrict__ rowptr) {
    const int t = threadIdx.x;
    const int gi = blockIdx.x * 256 + t;
    const int4 d4 = ((const int4*)deg)[gi];
    const int lsum = d4.x + d4.y + d4.z + d4.w;
    __shared__ int sh[256];
    sh[t] = lsum;
    __syncthreads();
    for (int o = 1; o < 256; o <<= 1) {
        int add = (t >= o) ? sh[t - o] : 0;
        __syncthreads();
        sh[t] += add;
        __syncthreads();
    }
    int base = blockOff[blockIdx.x] + sh[t] - lsum;
    int i0 = gi * 4;
    rowptr[i0 + 0] = base;
    rowptr[i0 + 1] = base + d4.x;
    rowptr[i0 + 2] = base + d4.x + d4.y;
    rowptr[i0 + 3] = base + d4.x + d4.y + d4.z;
}

// ---------------------------------------------------------------- bucket edges
__global__ __launch_bounds__(256) void k_bucket(const int* __restrict__ src,
                                                const int* __restrict__ dst,
                                                const float* __restrict__ dinv,
                                                const int* __restrict__ rowptr,
                                                int* __restrict__ cursor,
                                                int2* __restrict__ edat) {
    int e = blockIdx.x * 256 + threadIdx.x;
    if (e < N_EDGES) {
        int s = src[e], d = dst[e];
        float w = dinv[s] * dinv[d];
        int pos = rowptr[d] + atomicAdd(&cursor[d], 1);
        edat[pos] = make_int2(s, __float_as_int(w));
    }
}

// ---------------------------------------------------------------- GEMM
// Y[n][c] = bias[c] + sum_k X[n][k] * W[k][c]; fp32 math, fp16 output.
template<int K, int C, bool BN>
__global__ __launch_bounds__(256) void k_gemm(const float* __restrict__ X,
                                              const float* __restrict__ W,
                                              const float* __restrict__ bias,
                                              const float* __restrict__ se,
                                              const float* __restrict__ be,
                                              __half* __restrict__ Y,
                                              int nodesPerBlock) {
    constexpr int CG = C / 4;
    constexpr int NPASS = 256 / CG;
    constexpr int XP = K + 1;
    __shared__ __align__(16) float Ws[K * C];
    __shared__ float Xs[NPASS * XP];
    const int tid = threadIdx.x;
    for (int i = tid; i < K * C; i += 256) Ws[i] = W[i];
    const int cg = tid % CG;
    const int ln = tid / CG;
    const int c0 = cg * 4;
    const float4 bv = *(const float4*)&bias[c0];
    const int blockStart = blockIdx.x * nodesPerBlock;
    const int passes = nodesPerBlock / NPASS;
    for (int p = 0; p < passes; ++p) {
        const int node0 = blockStart + p * NPASS;
        __syncthreads();
        for (int i = tid; i < NPASS * K; i += 256) {
            int lnn = i / K, k = i % K;
            int n = node0 + lnn;
            float v = 0.0f;
            if (n < N_NODES) {
                v = X[(size_t)n * K + k];
                if (BN) v = fmaxf(v * se[k] + be[k], 0.0f);
            }
            Xs[lnn * XP + k] = v;
        }
        __syncthreads();
        const int n = node0 + ln;
        float4 acc = bv;
        const float* xrow = &Xs[ln * XP];
        #pragma unroll 8
        for (int k = 0; k < K; ++k) {
            float f = xrow[k];
            float4 w = *(const float4*)&Ws[k * C + c0];
            acc.x += f * w.x;
            acc.y += f * w.y;
            acc.z += f * w.z;
            acc.w += f * w.w;
        }
        if (n < N_NODES) {
            ushort4 sv;
            sv.x = __half_as_ushort(__float2half_rn(acc.x));
            sv.y = __half_as_ushort(__float2half_rn(acc.y));
            sv.z = __half_as_ushort(__float2half_rn(acc.z));
            sv.w = __half_as_ushort(__float2half_rn(acc.w));
            *(ushort4*)&Y[(size_t)n * C + c0] = sv;
        }
    }
}

// ---------------------------------------------------------------- gather-agg
// Sub-wave node slots: each lane holds 2 channels (__half2), so a node needs
// LPN = C/2 lanes -> 2 nodes per wave (C=64) or 4 (C=32). Each vector load
// instruction issues one row transaction PER SLOT -> 2-4x transactions in
// flight vs full-wave rows. The edat batch for the next 8 edges is prefetched
// (edn) so its miss overlaps the current batch's 8 h-row misses.
template<int C>
__global__ __launch_bounds__(256) void k_gather(const __half* __restrict__ h,
                                                const int* __restrict__ rowptr,
                                                const int2* __restrict__ edat,
                                                const float* __restrict__ gammaP,
                                                int r, int npb,
                                                float* __restrict__ X,
                                                float* __restrict__ bnsum,
                                                float* __restrict__ bnsq) {
    constexpr int LPN = C / 2;      // lanes per node
    constexpr int SPB = 256 / LPN;  // node slots per block (8 or 16)
    const int l    = threadIdx.x % LPN;   // channel-pair index
    const int slot = threadIdx.x / LPN;
    const float g = gammaP[r];
    const float gi = 1.0f - g;
    const int n0 = blockIdx.x * npb;
    const __half2* hl = (const __half2*)h + l;   // channel base, hoisted
    float2 s  = {0.0f, 0.0f};
    float2 sq = {0.0f, 0.0f};
    for (int i = slot; i < npb; i += SPB) {
        int n = n0 + i;
        if (n >= N_NODES) break;
        int rs = rowptr[n], re = rowptr[n + 1];
        const int efull = rs + ((re - rs) & ~7);
        float2 acc = {0.0f, 0.0f};
        int2 ed[8];
        if (rs < efull) {
            #pragma unroll
            for (int j = 0; j < 8; ++j) ed[j] = edat[rs + j];
        }
        for (int e = rs; e < efull; e += 8) {
            // prefetch next batch: miss overlaps this batch's h-row misses
            int2 edn[8];
            const int en = e + 8;
            const bool more = en < efull;
            #pragma unroll
            for (int j = 0; j < 8; ++j) edn[j] = edat[more ? en + j : rs];
            #pragma unroll
            for (int j = 0; j < 8; ++j) {
                float2 v = __half22float2(hl[(unsigned)ed[j].x * LPN]);
                float w = __int_as_float(ed[j].y);
                acc.x += v.x * w;
                acc.y += v.y * w;
            }
            #pragma unroll
            for (int j = 0; j < 8; ++j) ed[j] = edn[j];
        }
        if (efull < re) {   // single clamped tail batch
            #pragma unroll
            for (int j = 0; j < 8; ++j) {
                int t = efull + j;
                ed[j] = edat[(t < re) ? t : rs];
            }
            #pragma unroll
            for (int j = 0; j < 8; ++j) {
                float2 v = __half22float2(hl[(unsigned)ed[j].x * LPN]);
                float w = (efull + j < re) ? __int_as_float(ed[j].y) : 0.0f;
                acc.x += v.x * w;
                acc.y += v.y * w;
            }
        }
        float2 hv = __half22float2(hl[(unsigned)n * LPN]);
        float2 x;
        x.x = g * acc.x + gi * hv.x;
        x.y = g * acc.y + gi * hv.y;
        *(float2*)&X[(size_t)n * C + 2 * l] = x;
        s.x += x.x;  s.y += x.y;
        sq.x += x.x * x.x;  sq.y += x.y * x.y;
    }
    __shared__ float2 red[256];
    red[threadIdx.x] = s;
    __syncthreads();
    if (slot == 0) {
        float2 t = {0.0f, 0.0f};
        #pragma unroll
        for (int i = 0; i < SPB; ++i) {
            t.x += red[l + i * LPN].x;
            t.y += red[l + i * LPN].y;
        }
        atomicAdd(&bnsum[2 * l + 0], t.x);
        atomicAdd(&bnsum[2 * l + 1], t.y);
    }
    __syncthreads();
    red[threadIdx.x] = sq;
    __syncthreads();
    if (slot == 0) {
        float2 t = {0.0f, 0.0f};
        #pragma unroll
        for (int i = 0; i < SPB; ++i) {
            t.x += red[l + i * LPN].x;
            t.y += red[l + i * LPN].y;
        }
        atomicAdd(&bnsq[2 * l + 0], t.x);
        atomicAdd(&bnsq[2 * l + 1], t.y);
    }
}

// ---------------------------------------------------------------- BN finalize
template<int C>
__global__ void k_bnfin(const float* __restrict__ bnsum,
                        const float* __restrict__ bnsq,
                        const float* __restrict__ scale,
                        const float* __restrict__ bias,
                        float* __restrict__ se, float* __restrict__ be) {
    int c = threadIdx.x;
    if (c < C) {
        float m = bnsum[c] * (1.0f / N_NODES);
        float v = bnsq[c] * (1.0f / N_NODES) - m * m;
        float inv = rsqrtf(v + BN_EPS);
        float sc = inv * scale[c];
        se[c] = sc;
        be[c] = bias[c] - m * sc;
    }
}

// ---------------------------------------------------------------- output
__global__ __launch_bounds__(256) void k_out(const float* __restrict__ x2,
                                             const int* __restrict__ batch,
                                             const float* __restrict__ se,
                                             const float* __restrict__ be,
                                             float* __restrict__ out, int r) {
    int gid = blockIdx.x * 256 + threadIdx.x;
    int b = gid >> 5;
    int c = gid & 31;
    if (b < B_NODES) {
        int node = batch[b];
        float y = fmaxf(x2[(size_t)node * 32 + c] * se[c] + be[c], 0.0f);
        float m = y;
        #pragma unroll
        for (int off = 16; off; off >>= 1) m = fmaxf(m, __shfl_xor(m, off, 32));
        float ex = __expf(y - m);
        float ssum = ex;
        #pragma unroll
        for (int off = 16; off; off >>= 1) ssum += __shfl_xor(ssum, off, 32);
        out[(size_t)b * (N_REL * 32) + r * 32 + c] = (y - m) - __logf(ssum);
    }
}

// ---------------------------------------------------------------- launcher
extern "C" void kernel_launch(void* const* d_in, const int* in_sizes, int n_in,
                              void* d_out, int out_size, void* d_ws, size_t ws_size,
                              hipStream_t stream) {
    const float* features    = (const float*)d_in[0];
    const int*   edge_index  = (const int*)d_in[1];
    const int*   batch_nodes = (const int*)d_in[2];
    const float* W1          = (const float*)d_in[3];
    const float* b1          = (const float*)d_in[4];
    const float* W2          = (const float*)d_in[5];
    const float* b2          = (const float*)d_in[6];
    const float* gamma1      = (const float*)d_in[7];
    const float* gamma2      = (const float*)d_in[8];
    const float* bn1_scale   = (const float*)d_in[9];
    const float* bn1_bias    = (const float*)d_in[10];
    const float* bn2_scale   = (const float*)d_in[11];
    const float* bn2_bias    = (const float*)d_in[12];
    float* out = (float*)d_out;

    // ---- workspace layout (byte offsets, 16B aligned) ----
    char* wsB = (char*)d_ws;
    size_t off = 0;
    auto alloc = [&](size_t bytes) {
        void* p = wsB + off;
        off = (off + bytes + 15) & ~(size_t)15;
        return p;
    };
    // zero-region (one memset/relation): deg (padded) + cursor + bn sums
    int*   deg    = (int*)alloc((size_t)N_PAD * 4);
    int*   cursor = (int*)alloc((size_t)N_NODES * 4);
    float* bnsum1 = (float*)alloc(64 * 4);
    float* bnsq1  = (float*)alloc(64 * 4);
    float* bnsum2 = (float*)alloc(32 * 4);
    float* bnsq2  = (float*)alloc(32 * 4);
    const size_t zeroBytes = off;
    // non-zeroed scratch
    float* dinv      = (float*)alloc((size_t)N_NODES * 4);
    int*   rowptr    = (int*)alloc((size_t)(N_PAD + 1) * 4);
    int*   blockSums = (int*)alloc(128 * 4);
    int*   blockOff  = (int*)alloc(128 * 4);
    float* se1 = (float*)alloc(64 * 4);
    float* be1 = (float*)alloc(64 * 4);
    float* se2 = (float*)alloc(32 * 4);
    float* be2 = (float*)alloc(32 * 4);
    int2*   edat = (int2*)alloc((size_t)N_EDGES * 8);
    __half* h1   = (__half*)alloc((size_t)N_NODES * 64 * 2);   // fp16
    float*  x1   = (float*)alloc((size_t)N_NODES * 64 * 4);
    __half* h2   = (__half*)alloc((size_t)N_NODES * 32 * 2);   // fp16
    float*  x2   = (float*)h1;  // alias: h1 (12.8MB) dead after gather<64>

    const int nScanBlocks = N_PAD / 1024;  // 98

    for (int r = 0; r < N_REL; ++r) {
        const int* src = edge_index + (size_t)r * 2 * N_EDGES;
        const int* dst = src + N_EDGES;

        hipMemsetAsync(d_ws, 0, zeroBytes, stream);

        // ---- CSR build (reused by both convs) ----
        k_deg<<<(N_EDGES + 255) / 256, 256, 0, stream>>>(dst, deg);
        k_dinv<<<(N_NODES + 255) / 256, 256, 0, stream>>>(deg, dinv);
        k_blocksum<<<nScanBlocks, 256, 0, stream>>>(deg, blockSums);
        k_scanoff<<<1, 128, 0, stream>>>(blockSums, blockOff, rowptr, nScanBlocks);
        k_scan2<<<nScanBlocks, 256, 0, stream>>>(deg, blockOff, rowptr);
        k_bucket<<<(N_EDGES + 255) / 256, 256, 0, stream>>>(src, dst, dinv,
                                                            rowptr, cursor, edat);

        // ---- conv1 ----
        k_gemm<128, 64, false><<<(N_NODES + 63) / 64, 256, 0, stream>>>(
            features, W1 + (size_t)r * 128 * 64, b1 + r * 64,
            nullptr, nullptr, h1, 64);
        k_gather<64><<<(N_NODES + 31) / 32, 256, 0, stream>>>(
            h1, rowptr, edat, gamma1, r, 32, x1, bnsum1, bnsq1);
        k_bnfin<64><<<1, 64, 0, stream>>>(bnsum1, bnsq1,
            bn1_scale + r * 64, bn1_bias + r * 64, se1, be1);

        // ---- conv2 (BN+relu fused into GEMM load) ----
        k_gemm<64, 32, true><<<(N_NODES + 127) / 128, 256, 0, stream>>>(
            x1, W2 + (size_t)r * 64 * 32, b2 + r * 32, se1, be1, h2, 128);
        k_gather<32><<<(N_NODES + 63) / 64, 256, 0, stream>>>(
            h2, rowptr, edat, gamma2, r, 64, x2, bnsum2, bnsq2);
        k_bnfin<32><<<1, 32, 0, stream>>>(bnsum2, bnsq2,
            bn2_scale + r * 32, bn2_bias + r * 32, se2, be2);

        // ---- output ----
        k_out<<<(B_NODES * 32 + 255) / 256, 256, 0, stream>>>(
            x2, batch_nodes, se2, be2, out, r);
    }
}

// Round 7
// 1384.603 us; speedup vs baseline: 1.1604x; 1.1604x over previous
//
#include <hip/hip_runtime.h>
#include <hip/hip_fp16.h>
#include <math.h>

#define N_NODES 100000
#define N_PAD   100352   // 98 * 1024, for the scan kernels
#define N_EDGES 1600000
#define N_REL   3
#define F_DIM   128
#define H_DIM   64
#define O_DIM   32
#define B_NODES 50000
#define BN_EPS  1e-5f

// ---------------------------------------------------------------- degree (int)
__global__ __launch_bounds__(256) void k_deg(const int* __restrict__ dst,
                                             int* __restrict__ deg) {
    int e = blockIdx.x * 256 + threadIdx.x;
    if (e < N_EDGES) atomicAdd(&deg[dst[e]], 1);
}

__global__ __launch_bounds__(256) void k_dinv(const int* __restrict__ deg,
                                              float* __restrict__ dinv) {
    int n = blockIdx.x * 256 + threadIdx.x;
    if (n < N_NODES) dinv[n] = rsqrtf(fmaxf((float)deg[n], 1.0f));
}

// ---------------------------------------------------------------- scan phase A
__global__ __launch_bounds__(256) void k_blocksum(const int* __restrict__ deg,
                                                  int* __restrict__ blockSums) {
    const int t = threadIdx.x;
    const int4 d4 = ((const int4*)deg)[blockIdx.x * 256 + t];
    int lsum = d4.x + d4.y + d4.z + d4.w;
    __shared__ int sh[256];
    sh[t] = lsum;
    __syncthreads();
    for (int o = 128; o > 0; o >>= 1) {
        if (t < o) sh[t] += sh[t + o];
        __syncthreads();
    }
    if (t == 0) blockSums[blockIdx.x] = sh[0];
}

// ---------------------------------------------------------------- scan phase B
__global__ void k_scanoff(const int* __restrict__ blockSums,
                          int* __restrict__ blockOff,
                          int* __restrict__ rowptr, int nb) {
    __shared__ int sh[128];
    const int t = threadIdx.x;
    int v = (t < nb) ? blockSums[t] : 0;
    sh[t] = v;
    __syncthreads();
    for (int o = 1; o < 128; o <<= 1) {
        int add = (t >= o) ? sh[t - o] : 0;
        __syncthreads();
        sh[t] += add;
        __syncthreads();
    }
    if (t < nb) blockOff[t] = sh[t] - v;
    if (t == 0) rowptr[N_NODES] = N_EDGES;
}

// ---------------------------------------------------------------- scan phase C
__global__ __launch_bounds__(256) void k_scan2(const int* __restrict__ deg,
                                               const int* __restrict__ blockOff,
                                               int* __restrict__ rowptr) {
    const int t = threadIdx.x;
    const int gi = blockIdx.x * 256 + t;
    const int4 d4 = ((const int4*)deg)[gi];
    const int lsum = d4.x + d4.y + d4.z + d4.w;
    __shared__ int sh[256];
    sh[t] = lsum;
    __syncthreads();
    for (int o = 1; o < 256; o <<= 1) {
        int add = (t >= o) ? sh[t - o] : 0;
        __syncthreads();
        sh[t] += add;
        __syncthreads();
    }
    int base = blockOff[blockIdx.x] + sh[t] - lsum;
    int i0 = gi * 4;
    rowptr[i0 + 0] = base;
    rowptr[i0 + 1] = base + d4.x;
    rowptr[i0 + 2] = base + d4.x + d4.y;
    rowptr[i0 + 3] = base + d4.x + d4.y + d4.z;
}

// ---------------------------------------------------------------- bucket edges
__global__ __launch_bounds__(256) void k_bucket(const int* __restrict__ src,
                                                const int* __restrict__ dst,
                                                const float* __restrict__ dinv,
                                                const int* __restrict__ rowptr,
                                                int* __restrict__ cursor,
                                                int2* __restrict__ edat) {
    int e = blockIdx.x * 256 + threadIdx.x;
    if (e < N_EDGES) {
        int s = src[e], d = dst[e];
        float w = dinv[s] * dinv[d];
        int pos = rowptr[d] + atomicAdd(&cursor[d], 1);
        edat[pos] = make_int2(s, __float_as_int(w));
    }
}

// ---------------------------------------------------------------- GEMM
// Y[n][c] = bias[c] + sum_k X[n][k] * W[k][c]; fp32 math, fp16 output.
template<int K, int C, bool BN>
__global__ __launch_bounds__(256) void k_gemm(const float* __restrict__ X,
                                              const float* __restrict__ W,
                                              const float* __restrict__ bias,
                                              const float* __restrict__ se,
                                              const float* __restrict__ be,
                                              __half* __restrict__ Y,
                                              int nodesPerBlock) {
    constexpr int CG = C / 4;
    constexpr int NPASS = 256 / CG;
    constexpr int XP = K + 1;
    __shared__ __align__(16) float Ws[K * C];
    __shared__ float Xs[NPASS * XP];
    const int tid = threadIdx.x;
    for (int i = tid; i < K * C; i += 256) Ws[i] = W[i];
    const int cg = tid % CG;
    const int ln = tid / CG;
    const int c0 = cg * 4;
    const float4 bv = *(const float4*)&bias[c0];
    const int blockStart = blockIdx.x * nodesPerBlock;
    const int passes = nodesPerBlock / NPASS;
    for (int p = 0; p < passes; ++p) {
        const int node0 = blockStart + p * NPASS;
        __syncthreads();
        for (int i = tid; i < NPASS * K; i += 256) {
            int lnn = i / K, k = i % K;
            int n = node0 + lnn;
            float v = 0.0f;
            if (n < N_NODES) {
                v = X[(size_t)n * K + k];
                if (BN) v = fmaxf(v * se[k] + be[k], 0.0f);
            }
            Xs[lnn * XP + k] = v;
        }
        __syncthreads();
        const int n = node0 + ln;
        float4 acc = bv;
        const float* xrow = &Xs[ln * XP];
        #pragma unroll 8
        for (int k = 0; k < K; ++k) {
            float f = xrow[k];
            float4 w = *(const float4*)&Ws[k * C + c0];
            acc.x += f * w.x;
            acc.y += f * w.y;
            acc.z += f * w.z;
            acc.w += f * w.w;
        }
        if (n < N_NODES) {
            ushort4 sv;
            sv.x = __half_as_ushort(__float2half_rn(acc.x));
            sv.y = __half_as_ushort(__float2half_rn(acc.y));
            sv.z = __half_as_ushort(__float2half_rn(acc.z));
            sv.w = __half_as_ushort(__float2half_rn(acc.w));
            *(ushort4*)&Y[(size_t)n * C + c0] = sv;
        }
    }
}

// ---------------------------------------------------------------- gather-agg
// Block handles NPB nodes whose edat slice [rowptr[n0], rowptr[n0+NPB]) is
// CONTIGUOUS: stage it into LDS with coalesced loads (chunked for skew), then
// run the clamp-free 8-wide edge loop reading edge records from LDS — the
// only global traffic in the loop is the 8 independent h-row gathers, which
// stay in flight (no serialized edat miss between batches).
template<int C, int NPB>
__global__ __launch_bounds__(256) void k_gather(const __half* __restrict__ h,
                                                const int* __restrict__ rowptr,
                                                const int2* __restrict__ edat,
                                                const float* __restrict__ gammaP,
                                                int r,
                                                float* __restrict__ X,
                                                float* __restrict__ bnsum,
                                                float* __restrict__ bnsq) {
    constexpr int WPB = 256 / C;        // row slots per block
    constexpr int RPS = NPB / WPB;      // rows per slot
    constexpr int CH  = 2048;           // LDS edge chunk (16 KB)
    __shared__ int2 eds[CH];
    __shared__ int rp[NPB + 1];
    __shared__ float red[256];
    const int tid = threadIdx.x;
    const int c = tid % C;
    const int slot = tid / C;
    const float g = gammaP[r];
    const float gi = 1.0f - g;
    const int n0 = blockIdx.x * NPB;
    const __half* hc = h + c;           // per-lane channel base
    // stage rowptr slice
    if (tid <= NPB) {
        int n = n0 + tid;
        rp[tid] = rowptr[(n <= N_NODES) ? n : N_NODES];
    }
    __syncthreads();
    const int bs = rp[0];
    const int bEnd = rp[NPB];
    int rs[RPS], re[RPS];
    float acc[RPS];
    #pragma unroll
    for (int i = 0; i < RPS; ++i) {
        int ri = slot + i * WPB;
        rs[i] = rp[ri];
        re[i] = rp[ri + 1];
        acc[i] = 0.0f;
    }
    for (int c0 = bs; c0 < bEnd; c0 += CH) {
        const int c1 = min(c0 + CH, bEnd);
        const int cnt = c1 - c0;
        __syncthreads();
        for (int j = tid; j < cnt; j += 256) eds[j] = edat[c0 + j];
        __syncthreads();
        #pragma unroll
        for (int i = 0; i < RPS; ++i) {
            const int lo = max(rs[i], c0);
            const int hi = min(re[i], c1);
            if (lo >= hi) continue;
            float a = acc[i];
            int e = lo;
            const int efull = lo + ((hi - lo) & ~7);
            for (; e < efull; e += 8) {           // clamp-free main body
                int2 ed[8];
                #pragma unroll
                for (int j = 0; j < 8; ++j) ed[j] = eds[e - c0 + j];
                float v[8];
                #pragma unroll
                for (int j = 0; j < 8; ++j)
                    v[j] = __half2float(hc[(unsigned)ed[j].x * C]);
                #pragma unroll
                for (int j = 0; j < 8; ++j)
                    a += v[j] * __int_as_float(ed[j].y);
            }
            if (e < hi) {                         // single clamped tail batch
                int2 ed[8];
                #pragma unroll
                for (int j = 0; j < 8; ++j) {
                    int t = e + j;
                    ed[j] = eds[((t < hi) ? t : lo) - c0];
                }
                float v[8];
                #pragma unroll
                for (int j = 0; j < 8; ++j)
                    v[j] = __half2float(hc[(unsigned)ed[j].x * C]);
                #pragma unroll
                for (int j = 0; j < 8; ++j) {
                    float w = (e + j < hi) ? __int_as_float(ed[j].y) : 0.0f;
                    a += v[j] * w;
                }
            }
            acc[i] = a;
        }
    }
    // finalize: mix with self features, store, BN partial sums
    float s = 0.0f, sq = 0.0f;
    #pragma unroll
    for (int i = 0; i < RPS; ++i) {
        int n = n0 + slot + i * WPB;
        if (n < N_NODES) {
            float x = g * acc[i] + gi * __half2float(hc[(unsigned)n * C]);
            X[(size_t)n * C + c] = x;
            s += x;
            sq += x * x;
        }
    }
    __syncthreads();
    red[tid] = s;
    __syncthreads();
    if (slot == 0) {
        float t = 0.0f;
        #pragma unroll
        for (int i = 0; i < WPB; ++i) t += red[c + i * C];
        atomicAdd(&bnsum[c], t);
    }
    __syncthreads();
    red[tid] = sq;
    __syncthreads();
    if (slot == 0) {
        float t = 0.0f;
        #pragma unroll
        for (int i = 0; i < WPB; ++i) t += red[c + i * C];
        atomicAdd(&bnsq[c], t);
    }
}

// ---------------------------------------------------------------- BN finalize
template<int C>
__global__ void k_bnfin(const float* __restrict__ bnsum,
                        const float* __restrict__ bnsq,
                        const float* __restrict__ scale,
                        const float* __restrict__ bias,
                        float* __restrict__ se, float* __restrict__ be) {
    int c = threadIdx.x;
    if (c < C) {
        float m = bnsum[c] * (1.0f / N_NODES);
        float v = bnsq[c] * (1.0f / N_NODES) - m * m;
        float inv = rsqrtf(v + BN_EPS);
        float sc = inv * scale[c];
        se[c] = sc;
        be[c] = bias[c] - m * sc;
    }
}

// ---------------------------------------------------------------- output
__global__ __launch_bounds__(256) void k_out(const float* __restrict__ x2,
                                             const int* __restrict__ batch,
                                             const float* __restrict__ se,
                                             const float* __restrict__ be,
                                             float* __restrict__ out, int r) {
    int gid = blockIdx.x * 256 + threadIdx.x;
    int b = gid >> 5;
    int c = gid & 31;
    if (b < B_NODES) {
        int node = batch[b];
        float y = fmaxf(x2[(size_t)node * 32 + c] * se[c] + be[c], 0.0f);
        float m = y;
        #pragma unroll
        for (int off = 16; off; off >>= 1) m = fmaxf(m, __shfl_xor(m, off, 32));
        float ex = __expf(y - m);
        float ssum = ex;
        #pragma unroll
        for (int off = 16; off; off >>= 1) ssum += __shfl_xor(ssum, off, 32);
        out[(size_t)b * (N_REL * 32) + r * 32 + c] = (y - m) - __logf(ssum);
    }
}

// ---------------------------------------------------------------- launcher
extern "C" void kernel_launch(void* const* d_in, const int* in_sizes, int n_in,
                              void* d_out, int out_size, void* d_ws, size_t ws_size,
                              hipStream_t stream) {
    const float* features    = (const float*)d_in[0];
    const int*   edge_index  = (const int*)d_in[1];
    const int*   batch_nodes = (const int*)d_in[2];
    const float* W1          = (const float*)d_in[3];
    const float* b1          = (const float*)d_in[4];
    const float* W2          = (const float*)d_in[5];
    const float* b2          = (const float*)d_in[6];
    const float* gamma1      = (const float*)d_in[7];
    const float* gamma2      = (const float*)d_in[8];
    const float* bn1_scale   = (const float*)d_in[9];
    const float* bn1_bias    = (const float*)d_in[10];
    const float* bn2_scale   = (const float*)d_in[11];
    const float* bn2_bias    = (const float*)d_in[12];
    float* out = (float*)d_out;

    // ---- workspace layout (byte offsets, 16B aligned) ----
    char* wsB = (char*)d_ws;
    size_t off = 0;
    auto alloc = [&](size_t bytes) {
        void* p = wsB + off;
        off = (off + bytes + 15) & ~(size_t)15;
        return p;
    };
    // zero-region (one memset/relation): deg (padded) + cursor + bn sums
    int*   deg    = (int*)alloc((size_t)N_PAD * 4);
    int*   cursor = (int*)alloc((size_t)N_NODES * 4);
    float* bnsum1 = (float*)alloc(64 * 4);
    float* bnsq1  = (float*)alloc(64 * 4);
    float* bnsum2 = (float*)alloc(32 * 4);
    float* bnsq2  = (float*)alloc(32 * 4);
    const size_t zeroBytes = off;
    // non-zeroed scratch
    float* dinv      = (float*)alloc((size_t)N_NODES * 4);
    int*   rowptr    = (int*)alloc((size_t)(N_PAD + 1) * 4);
    int*   blockSums = (int*)alloc(128 * 4);
    int*   blockOff  = (int*)alloc(128 * 4);
    float* se1 = (float*)alloc(64 * 4);
    float* be1 = (float*)alloc(64 * 4);
    float* se2 = (float*)alloc(32 * 4);
    float* be2 = (float*)alloc(32 * 4);
    int2*   edat = (int2*)alloc((size_t)N_EDGES * 8);
    __half* h1   = (__half*)alloc((size_t)N_NODES * 64 * 2);   // fp16
    float*  x1   = (float*)alloc((size_t)N_NODES * 64 * 4);
    __half* h2   = (__half*)alloc((size_t)N_NODES * 32 * 2);   // fp16
    float*  x2   = (float*)h1;  // alias: h1 (12.8MB) dead after gather<64>

    const int nScanBlocks = N_PAD / 1024;  // 98

    for (int r = 0; r < N_REL; ++r) {
        const int* src = edge_index + (size_t)r * 2 * N_EDGES;
        const int* dst = src + N_EDGES;

        hipMemsetAsync(d_ws, 0, zeroBytes, stream);

        // ---- CSR build (reused by both convs) ----
        k_deg<<<(N_EDGES + 255) / 256, 256, 0, stream>>>(dst, deg);
        k_dinv<<<(N_NODES + 255) / 256, 256, 0, stream>>>(deg, dinv);
        k_blocksum<<<nScanBlocks, 256, 0, stream>>>(deg, blockSums);
        k_scanoff<<<1, 128, 0, stream>>>(blockSums, blockOff, rowptr, nScanBlocks);
        k_scan2<<<nScanBlocks, 256, 0, stream>>>(deg, blockOff, rowptr);
        k_bucket<<<(N_EDGES + 255) / 256, 256, 0, stream>>>(src, dst, dinv,
                                                            rowptr, cursor, edat);

        // ---- conv1 ----
        k_gemm<128, 64, false><<<(N_NODES + 63) / 64, 256, 0, stream>>>(
            features, W1 + (size_t)r * 128 * 64, b1 + r * 64,
            nullptr, nullptr, h1, 64);
        k_gather<64, 32><<<(N_NODES + 31) / 32, 256, 0, stream>>>(
            h1, rowptr, edat, gamma1, r, x1, bnsum1, bnsq1);
        k_bnfin<64><<<1, 64, 0, stream>>>(bnsum1, bnsq1,
            bn1_scale + r * 64, bn1_bias + r * 64, se1, be1);

        // ---- conv2 (BN+relu fused into GEMM load) ----
        k_gemm<64, 32, true><<<(N_NODES + 127) / 128, 256, 0, stream>>>(
            x1, W2 + (size_t)r * 64 * 32, b2 + r * 32, se1, be1, h2, 128);
        k_gather<32, 64><<<(N_NODES + 63) / 64, 256, 0, stream>>>(
            h2, rowptr, edat, gamma2, r, x2, bnsum2, bnsq2);
        k_bnfin<32><<<1, 32, 0, stream>>>(bnsum2, bnsq2,
            bn2_scale + r * 32, bn2_bias + r * 32, se2, be2);

        // ---- output ----
        k_out<<<(B_NODES * 32 + 255) / 256, 256, 0, stream>>>(
            x2, batch_nodes, se2, be2, out, r);
    }
}

// Round 9
// 1096.705 us; speedup vs baseline: 1.4650x; 1.2625x over previous
//
#include <hip/hip_runtime.h>
#include <hip/hip_fp16.h>
#include <math.h>

#define N_NODES 100000
#define N_PAD   100352   // 98 * 1024, for the scan kernels
#define NSCAN   98       // N_PAD / 1024
#define N_EDGES 1600000
#define N_REL   3
#define BN_EPS  1e-5f

// All kernels are relation-batched: blockIdx.y (or blockIdx.x for the tiny
// ones) selects the relation r. 13 dispatches per call instead of 42.

// ---------------------------------------------------------------- degree
__global__ __launch_bounds__(256) void k_deg(const int* __restrict__ ei,
                                             int* __restrict__ deg) {
    const int r = blockIdx.y;
    const int* dst = ei + (size_t)r * 2 * N_EDGES + N_EDGES;
    int* dr = deg + (size_t)r * N_PAD;
    int e = blockIdx.x * 256 + threadIdx.x;
    if (e < N_EDGES) atomicAdd(&dr[dst[e]], 1);
}

// ---------------------------------------------------------------- blocksum + dinv (fused)
__global__ __launch_bounds__(256) void k_blocksum(const int* __restrict__ deg,
                                                  int* __restrict__ blockSums,
                                                  float* __restrict__ dinv) {
    const int r = blockIdx.y;
    const int t = threadIdx.x;
    const int gi = blockIdx.x * 256 + t;
    const int4 d4 = ((const int4*)(deg + (size_t)r * N_PAD))[gi];
    float4 dv;
    dv.x = rsqrtf(fmaxf((float)d4.x, 1.0f));
    dv.y = rsqrtf(fmaxf((float)d4.y, 1.0f));
    dv.z = rsqrtf(fmaxf((float)d4.z, 1.0f));
    dv.w = rsqrtf(fmaxf((float)d4.w, 1.0f));
    ((float4*)(dinv + (size_t)r * N_PAD))[gi] = dv;
    int lsum = d4.x + d4.y + d4.z + d4.w;
    __shared__ int sh[256];
    sh[t] = lsum;
    __syncthreads();
    for (int o = 128; o > 0; o >>= 1) {
        if (t < o) sh[t] += sh[t + o];
        __syncthreads();
    }
    if (t == 0) blockSums[r * 128 + blockIdx.x] = sh[0];
}

// ---------------------------------------------------------------- scan of block sums
__global__ void k_scanoff(const int* __restrict__ blockSums,
                          int* __restrict__ blockOff,
                          int* __restrict__ rowptr) {
    const int r = blockIdx.x;
    __shared__ int sh[128];
    const int t = threadIdx.x;
    int v = (t < NSCAN) ? blockSums[r * 128 + t] : 0;
    sh[t] = v;
    __syncthreads();
    for (int o = 1; o < 128; o <<= 1) {
        int add = (t >= o) ? sh[t - o] : 0;
        __syncthreads();
        sh[t] += add;
        __syncthreads();
    }
    if (t < NSCAN) blockOff[r * 128 + t] = sh[t] - v;
    if (t == 0) rowptr[(size_t)r * (N_PAD + 1) + N_NODES] = N_EDGES;
}

// ---------------------------------------------------------------- full exclusive scan
__global__ __launch_bounds__(256) void k_scan2(const int* __restrict__ deg,
                                               const int* __restrict__ blockOff,
                                               int* __restrict__ rowptr) {
    const int r = blockIdx.y;
    const int t = threadIdx.x;
    const int gi = blockIdx.x * 256 + t;
    const int4 d4 = ((const int4*)(deg + (size_t)r * N_PAD))[gi];
    const int lsum = d4.x + d4.y + d4.z + d4.w;
    __shared__ int sh[256];
    sh[t] = lsum;
    __syncthreads();
    for (int o = 1; o < 256; o <<= 1) {
        int add = (t >= o) ? sh[t - o] : 0;
        __syncthreads();
        sh[t] += add;
        __syncthreads();
    }
    int* rp = rowptr + (size_t)r * (N_PAD + 1);
    int base = blockOff[r * 128 + blockIdx.x] + sh[t] - lsum;
    int i0 = gi * 4;
    rp[i0 + 0] = base;
    rp[i0 + 1] = base + d4.x;
    rp[i0 + 2] = base + d4.x + d4.y;
    rp[i0 + 3] = base + d4.x + d4.y + d4.z;
}

// ---------------------------------------------------------------- bucket edges
__global__ __launch_bounds__(256) void k_bucket(const int* __restrict__ ei,
                                                const float* __restrict__ dinv,
                                                const int* __restrict__ rowptr,
                                                int* __restrict__ cursor,
                                                int2* __restrict__ edat) {
    const int r = blockIdx.y;
    const int* src = ei + (size_t)r * 2 * N_EDGES;
    const int* dst = src + N_EDGES;
    const float* dv = dinv + (size_t)r * N_PAD;
    const int* rp = rowptr + (size_t)r * (N_PAD + 1);
    int* cur = cursor + (size_t)r * N_NODES;
    int2* ed = edat + (size_t)r * N_EDGES;
    int e = blockIdx.x * 256 + threadIdx.x;
    if (e < N_EDGES) {
        int s = src[e], d = dst[e];
        float w = dv[s] * dv[d];
        int pos = rp[d] + atomicAdd(&cur[d], 1);
        ed[pos] = make_int2(s, __float_as_int(w));
    }
}

// ---------------------------------------------------------------- GEMM
// Y[n][c] = bias[c] + sum_k X[n][k] * W[k][c]; fp32 math, fp16 output.
// xStrideR = per-relation stride of X (0 -> shared input, e.g. features).
// NOTE: fused BN scale/bias (se/be) act on the INPUT dim -> per-relation
// stride is K (not C). This was the r8 bug.
__device__ __forceinline__ float ld_f(const float* p)  { return *p; }
__device__ __forceinline__ float ld_f(const __half* p) { return __half2float(*p); }

template<int K, int C, bool BN, typename TI>
__global__ __launch_bounds__(256) void k_gemm(const TI* __restrict__ Xb,
                                              size_t xStrideR,
                                              const float* __restrict__ Wb,
                                              const float* __restrict__ biasB,
                                              const float* __restrict__ seB,
                                              const float* __restrict__ beB,
                                              __half* __restrict__ Yb,
                                              int nodesPerBlock) {
    const int r = blockIdx.y;
    const TI* X = Xb + (size_t)r * xStrideR;
    const float* W = Wb + (size_t)r * K * C;
    const float* bias = biasB + (size_t)r * C;
    const float* se = BN ? seB + (size_t)r * K : nullptr;   // K-stride!
    const float* be = BN ? beB + (size_t)r * K : nullptr;   // K-stride!
    __half* Y = Yb + (size_t)r * N_NODES * C;

    constexpr int CG = C / 4;
    constexpr int NPASS = 256 / CG;
    constexpr int XP = K + 1;
    __shared__ __align__(16) float Ws[K * C];
    __shared__ float Xs[NPASS * XP];
    const int tid = threadIdx.x;
    for (int i = tid; i < K * C; i += 256) Ws[i] = W[i];
    const int cg = tid % CG;
    const int ln = tid / CG;
    const int c0 = cg * 4;
    const float4 bv = *(const float4*)&bias[c0];
    const int blockStart = blockIdx.x * nodesPerBlock;
    const int passes = nodesPerBlock / NPASS;
    for (int p = 0; p < passes; ++p) {
        const int node0 = blockStart + p * NPASS;
        __syncthreads();
        for (int i = tid; i < NPASS * K; i += 256) {
            int lnn = i / K, k = i % K;
            int n = node0 + lnn;
            float v = 0.0f;
            if (n < N_NODES) {
                v = ld_f(&X[(size_t)n * K + k]);
                if (BN) v = fmaxf(v * se[k] + be[k], 0.0f);
            }
            Xs[lnn * XP + k] = v;
        }
        __syncthreads();
        const int n = node0 + ln;
        float4 acc = bv;
        const float* xrow = &Xs[ln * XP];
        #pragma unroll 8
        for (int k = 0; k < K; ++k) {
            float f = xrow[k];
            float4 w = *(const float4*)&Ws[k * C + c0];
            acc.x += f * w.x;
            acc.y += f * w.y;
            acc.z += f * w.z;
            acc.w += f * w.w;
        }
        if (n < N_NODES) {
            ushort4 sv;
            sv.x = __half_as_ushort(__float2half_rn(acc.x));
            sv.y = __half_as_ushort(__float2half_rn(acc.y));
            sv.z = __half_as_ushort(__float2half_rn(acc.z));
            sv.w = __half_as_ushort(__float2half_rn(acc.w));
            *(ushort4*)&Y[(size_t)n * C + c0] = sv;
        }
    }
}

// ---------------------------------------------------------------- gather-agg
// Block handles NPB nodes whose edat slice is contiguous: stage it in LDS
// (coalesced, chunked for skew), then clamp-free 8-wide edge loop with only
// the 8 independent h-row gathers as global traffic. Fused gamma-mix + BN
// partial stats. TO = output element type (fp16 for x1, fp32 for x2).
template<int C, int NPB, typename TO>
__global__ __launch_bounds__(256) void k_gather(const __half* __restrict__ hB,
                                                const int* __restrict__ rowptrB,
                                                const int2* __restrict__ edatB,
                                                const float* __restrict__ gammaP,
                                                TO* __restrict__ XB,
                                                float* __restrict__ bnsumB,
                                                float* __restrict__ bnsqB) {
    const int r = blockIdx.y;
    const __half* h = hB + (size_t)r * N_NODES * C;
    const int* rowptr = rowptrB + (size_t)r * (N_PAD + 1);
    const int2* edat = edatB + (size_t)r * N_EDGES;
    TO* X = XB + (size_t)r * N_NODES * C;
    float* bnsum = bnsumB + (size_t)r * C;
    float* bnsq  = bnsqB  + (size_t)r * C;

    constexpr int WPB = 256 / C;        // row slots per block
    constexpr int RPS = NPB / WPB;      // rows per slot
    constexpr int CH  = 2048;           // LDS edge chunk (16 KB)
    __shared__ int2 eds[CH];
    __shared__ int rp[NPB + 1];
    __shared__ float red[256];
    const int tid = threadIdx.x;
    const int c = tid % C;
    const int slot = tid / C;
    const float g = gammaP[r];
    const float gi = 1.0f - g;
    const int n0 = blockIdx.x * NPB;
    const __half* hc = h + c;
    if (tid <= NPB) {
        int n = n0 + tid;
        rp[tid] = rowptr[(n <= N_NODES) ? n : N_NODES];
    }
    __syncthreads();
    const int bs = rp[0];
    const int bEnd = rp[NPB];
    int rs[RPS], re[RPS];
    float acc[RPS];
    #pragma unroll
    for (int i = 0; i < RPS; ++i) {
        int ri = slot + i * WPB;
        rs[i] = rp[ri];
        re[i] = rp[ri + 1];
        acc[i] = 0.0f;
    }
    for (int ck = bs; ck < bEnd; ck += CH) {
        const int c1 = min(ck + CH, bEnd);
        const int cnt = c1 - ck;
        __syncthreads();
        for (int j = tid; j < cnt; j += 256) eds[j] = edat[ck + j];
        __syncthreads();
        #pragma unroll
        for (int i = 0; i < RPS; ++i) {
            const int lo = max(rs[i], ck);
            const int hi = min(re[i], c1);
            if (lo >= hi) continue;
            float a = acc[i];
            int e = lo;
            const int efull = lo + ((hi - lo) & ~7);
            for (; e < efull; e += 8) {           // clamp-free main body
                int2 ed[8];
                #pragma unroll
                for (int j = 0; j < 8; ++j) ed[j] = eds[e - ck + j];
                float v[8];
                #pragma unroll
                for (int j = 0; j < 8; ++j)
                    v[j] = __half2float(hc[(unsigned)ed[j].x * C]);
                #pragma unroll
                for (int j = 0; j < 8; ++j)
                    a += v[j] * __int_as_float(ed[j].y);
            }
            if (e < hi) {                         // single clamped tail batch
                int2 ed[8];
                #pragma unroll
                for (int j = 0; j < 8; ++j) {
                    int t = e + j;
                    ed[j] = eds[((t < hi) ? t : lo) - ck];
                }
                float v[8];
                #pragma unroll
                for (int j = 0; j < 8; ++j)
                    v[j] = __half2float(hc[(unsigned)ed[j].x * C]);
                #pragma unroll
                for (int j = 0; j < 8; ++j) {
                    float w = (e + j < hi) ? __int_as_float(ed[j].y) : 0.0f;
                    a += v[j] * w;
                }
            }
            acc[i] = a;
        }
    }
    // finalize: mix with self features, store, BN partial sums (fp32)
    float s = 0.0f, sq = 0.0f;
    #pragma unroll
    for (int i = 0; i < RPS; ++i) {
        int n = n0 + slot + i * WPB;
        if (n < N_NODES) {
            float x = g * acc[i] + gi * __half2float(hc[(unsigned)n * C]);
            if constexpr (sizeof(TO) == 2)
                X[(size_t)n * C + c] = __float2half_rn(x);
            else
                X[(size_t)n * C + c] = x;
            s += x;
            sq += x * x;
        }
    }
    __syncthreads();
    red[tid] = s;
    __syncthreads();
    if (slot == 0) {
        float t = 0.0f;
        #pragma unroll
        for (int i = 0; i < WPB; ++i) t += red[c + i * C];
        atomicAdd(&bnsum[c], t);
    }
    __syncthreads();
    red[tid] = sq;
    __syncthreads();
    if (slot == 0) {
        float t = 0.0f;
        #pragma unroll
        for (int i = 0; i < WPB; ++i) t += red[c + i * C];
        atomicAdd(&bnsq[c], t);
    }
}

// ---------------------------------------------------------------- BN finalize
template<int C>
__global__ void k_bnfin(const float* __restrict__ bnsum,
                        const float* __restrict__ bnsq,
                        const float* __restrict__ scale,
                        const float* __restrict__ bias,
                        float* __restrict__ se, float* __restrict__ be) {
    const int r = blockIdx.x;
    int c = threadIdx.x;
    if (c < C) {
        int i = r * C + c;
        float m = bnsum[i] * (1.0f / N_NODES);
        float v = bnsq[i] * (1.0f / N_NODES) - m * m;
        float inv = rsqrtf(v + BN_EPS);
        float sc = inv * scale[i];
        se[i] = sc;
        be[i] = bias[i] - m * sc;
    }
}

// ---------------------------------------------------------------- output
__global__ __launch_bounds__(256) void k_out(const float* __restrict__ x2B,
                                             const int* __restrict__ batch,
                                             const float* __restrict__ seB,
                                             const float* __restrict__ beB,
                                             float* __restrict__ out) {
    const int r = blockIdx.y;
    const float* x2 = x2B + (size_t)r * N_NODES * 32;
    const float* se = seB + r * 32;
    const float* be = beB + r * 32;
    int gid = blockIdx.x * 256 + threadIdx.x;
    int b = gid >> 5;
    int c = gid & 31;
    if (b < 50000) {
        int node = batch[b];
        float y = fmaxf(x2[(size_t)node * 32 + c] * se[c] + be[c], 0.0f);
        float m = y;
        #pragma unroll
        for (int off = 16; off; off >>= 1) m = fmaxf(m, __shfl_xor(m, off, 32));
        float ex = __expf(y - m);
        float ssum = ex;
        #pragma unroll
        for (int off = 16; off; off >>= 1) ssum += __shfl_xor(ssum, off, 32);
        out[(size_t)b * (N_REL * 32) + r * 32 + c] = (y - m) - __logf(ssum);
    }
}

// ---------------------------------------------------------------- launcher
extern "C" void kernel_launch(void* const* d_in, const int* in_sizes, int n_in,
                              void* d_out, int out_size, void* d_ws, size_t ws_size,
                              hipStream_t stream) {
    const float* features    = (const float*)d_in[0];
    const int*   edge_index  = (const int*)d_in[1];
    const int*   batch_nodes = (const int*)d_in[2];
    const float* W1          = (const float*)d_in[3];
    const float* b1          = (const float*)d_in[4];
    const float* W2          = (const float*)d_in[5];
    const float* b2          = (const float*)d_in[6];
    const float* gamma1      = (const float*)d_in[7];
    const float* gamma2      = (const float*)d_in[8];
    const float* bn1_scale   = (const float*)d_in[9];
    const float* bn1_bias    = (const float*)d_in[10];
    const float* bn2_scale   = (const float*)d_in[11];
    const float* bn2_bias    = (const float*)d_in[12];
    float* out = (float*)d_out;

    // ---- workspace layout (byte offsets, 16B aligned), relation-batched ----
    char* wsB = (char*)d_ws;
    size_t off = 0;
    auto alloc = [&](size_t bytes) {
        void* p = wsB + off;
        off = (off + bytes + 15) & ~(size_t)15;
        return p;
    };
    // zero-region (single memset): deg (padded) + cursor + bn sums, all rel
    int*   deg    = (int*)alloc((size_t)N_REL * N_PAD * 4);
    int*   cursor = (int*)alloc((size_t)N_REL * N_NODES * 4);
    float* bnsum1 = (float*)alloc(N_REL * 64 * 4);
    float* bnsq1  = (float*)alloc(N_REL * 64 * 4);
    float* bnsum2 = (float*)alloc(N_REL * 32 * 4);
    float* bnsq2  = (float*)alloc(N_REL * 32 * 4);
    const size_t zeroBytes = off;
    // non-zeroed scratch
    float* dinv      = (float*)alloc((size_t)N_REL * N_PAD * 4);
    int*   rowptr    = (int*)alloc((size_t)N_REL * (N_PAD + 1) * 4);
    int*   blockSums = (int*)alloc(N_REL * 128 * 4);
    int*   blockOff  = (int*)alloc(N_REL * 128 * 4);
    float* se1 = (float*)alloc(N_REL * 64 * 4);
    float* be1 = (float*)alloc(N_REL * 64 * 4);
    float* se2 = (float*)alloc(N_REL * 32 * 4);
    float* be2 = (float*)alloc(N_REL * 32 * 4);
    int2*   edat = (int2*)alloc((size_t)N_REL * N_EDGES * 8);
    __half* h1   = (__half*)alloc((size_t)N_REL * N_NODES * 64 * 2); // 38.4 MB
    __half* x1   = (__half*)alloc((size_t)N_REL * N_NODES * 64 * 2); // 19.2 MB
    __half* h2   = (__half*)alloc((size_t)N_REL * N_NODES * 32 * 2); //  9.6 MB
    float*  x2   = (float*)h1;  // alias: h1 dead after gather64; needs 38.4 MB

    hipMemsetAsync(d_ws, 0, zeroBytes, stream);

    // ---- CSR build (all relations) ----
    k_deg<<<dim3((N_EDGES + 255) / 256, N_REL), 256, 0, stream>>>(edge_index, deg);
    k_blocksum<<<dim3(NSCAN, N_REL), 256, 0, stream>>>(deg, blockSums, dinv);
    k_scanoff<<<N_REL, 128, 0, stream>>>(blockSums, blockOff, rowptr);
    k_scan2<<<dim3(NSCAN, N_REL), 256, 0, stream>>>(deg, blockOff, rowptr);
    k_bucket<<<dim3((N_EDGES + 255) / 256, N_REL), 256, 0, stream>>>(
        edge_index, dinv, rowptr, cursor, edat);

    // ---- conv1 ----
    k_gemm<128, 64, false, float><<<dim3((N_NODES + 63) / 64, N_REL), 256, 0, stream>>>(
        features, 0, W1, b1, nullptr, nullptr, h1, 64);
    k_gather<64, 32, __half><<<dim3((N_NODES + 31) / 32, N_REL), 256, 0, stream>>>(
        h1, rowptr, edat, gamma1, x1, bnsum1, bnsq1);
    k_bnfin<64><<<N_REL, 64, 0, stream>>>(bnsum1, bnsq1, bn1_scale, bn1_bias, se1, be1);

    // ---- conv2 (BN+relu fused into GEMM load) ----
    k_gemm<64, 32, true, __half><<<dim3((N_NODES + 127) / 128, N_REL), 256, 0, stream>>>(
        x1, (size_t)N_NODES * 64, W2, b2, se1, be1, h2, 128);
    k_gather<32, 64, float><<<dim3((N_NODES + 63) / 64, N_REL), 256, 0, stream>>>(
        h2, rowptr, edat, gamma2, x2, bnsum2, bnsq2);
    k_bnfin<32><<<N_REL, 32, 0, stream>>>(bnsum2, bnsq2, bn2_scale, bn2_bias, se2, be2);

    // ---- output ----
    k_out<<<dim3((50000 * 32 + 255) / 256, N_REL), 256, 0, stream>>>(
        x2, batch_nodes, se2, be2, out);
}

// Round 10
// 1068.788 us; speedup vs baseline: 1.5032x; 1.0261x over previous
//
#include <hip/hip_runtime.h>
#include <hip/hip_fp16.h>
#include <math.h>

#define N_NODES 100000
#define N_PAD   100352   // 98 * 1024, for the scan kernels
#define NSCAN   98       // N_PAD / 1024
#define N_EDGES 1600000
#define N_REL   3
#define BN_EPS  1e-5f

// All kernels are relation-batched: blockIdx.y (or blockIdx.x for the tiny
// ones) selects the relation r. 13 dispatches per call.
//
// Key factorization: agg[n] = dinv[n] * sum_{e->n} hs[src_e], with
// hs = h * dinv prescaled in the GEMM epilogue. The edge record is then just
// the 4-byte src index (halves bucket-scatter write footprint, removes all
// per-edge dinv loads); the self term is recovered as hs[n]*rdinv[n].

// ---------------------------------------------------------------- degree
__global__ __launch_bounds__(256) void k_deg(const int* __restrict__ ei,
                                             int* __restrict__ deg) {
    const int r = blockIdx.y;
    const int* dst = ei + (size_t)r * 2 * N_EDGES + N_EDGES;
    int* dr = deg + (size_t)r * N_PAD;
    int e = blockIdx.x * 256 + threadIdx.x;
    if (e < N_EDGES) atomicAdd(&dr[dst[e]], 1);
}

// ------------------------------------------------ blocksum + dinv/rdinv (fused)
__global__ __launch_bounds__(256) void k_blocksum(const int* __restrict__ deg,
                                                  int* __restrict__ blockSums,
                                                  float* __restrict__ dinv,
                                                  float* __restrict__ rdinv) {
    const int r = blockIdx.y;
    const int t = threadIdx.x;
    const int gi = blockIdx.x * 256 + t;
    const int4 d4 = ((const int4*)(deg + (size_t)r * N_PAD))[gi];
    float4 m;
    m.x = fmaxf((float)d4.x, 1.0f);
    m.y = fmaxf((float)d4.y, 1.0f);
    m.z = fmaxf((float)d4.z, 1.0f);
    m.w = fmaxf((float)d4.w, 1.0f);
    float4 dv, rv;
    dv.x = rsqrtf(m.x); rv.x = m.x * dv.x;   // sqrt(m) = m * rsqrt(m)
    dv.y = rsqrtf(m.y); rv.y = m.y * dv.y;
    dv.z = rsqrtf(m.z); rv.z = m.z * dv.z;
    dv.w = rsqrtf(m.w); rv.w = m.w * dv.w;
    ((float4*)(dinv  + (size_t)r * N_PAD))[gi] = dv;
    ((float4*)(rdinv + (size_t)r * N_PAD))[gi] = rv;
    int lsum = d4.x + d4.y + d4.z + d4.w;
    __shared__ int sh[256];
    sh[t] = lsum;
    __syncthreads();
    for (int o = 128; o > 0; o >>= 1) {
        if (t < o) sh[t] += sh[t + o];
        __syncthreads();
    }
    if (t == 0) blockSums[r * 128 + blockIdx.x] = sh[0];
}

// ---------------------------------------------------------------- scan of block sums
__global__ void k_scanoff(const int* __restrict__ blockSums,
                          int* __restrict__ blockOff,
                          int* __restrict__ rowptr) {
    const int r = blockIdx.x;
    __shared__ int sh[128];
    const int t = threadIdx.x;
    int v = (t < NSCAN) ? blockSums[r * 128 + t] : 0;
    sh[t] = v;
    __syncthreads();
    for (int o = 1; o < 128; o <<= 1) {
        int add = (t >= o) ? sh[t - o] : 0;
        __syncthreads();
        sh[t] += add;
        __syncthreads();
    }
    if (t < NSCAN) blockOff[r * 128 + t] = sh[t] - v;
    if (t == 0) rowptr[(size_t)r * (N_PAD + 1) + N_NODES] = N_EDGES;
}

// ---------------------------------------------------------------- full exclusive scan
__global__ __launch_bounds__(256) void k_scan2(const int* __restrict__ deg,
                                               const int* __restrict__ blockOff,
                                               int* __restrict__ rowptr) {
    const int r = blockIdx.y;
    const int t = threadIdx.x;
    const int gi = blockIdx.x * 256 + t;
    const int4 d4 = ((const int4*)(deg + (size_t)r * N_PAD))[gi];
    const int lsum = d4.x + d4.y + d4.z + d4.w;
    __shared__ int sh[256];
    sh[t] = lsum;
    __syncthreads();
    for (int o = 1; o < 256; o <<= 1) {
        int add = (t >= o) ? sh[t - o] : 0;
        __syncthreads();
        sh[t] += add;
        __syncthreads();
    }
    int* rp = rowptr + (size_t)r * (N_PAD + 1);
    int base = blockOff[r * 128 + blockIdx.x] + sh[t] - lsum;
    int i0 = gi * 4;
    rp[i0 + 0] = base;
    rp[i0 + 1] = base + d4.x;
    rp[i0 + 2] = base + d4.x + d4.y;
    rp[i0 + 3] = base + d4.x + d4.y + d4.z;
}

// ---------------------------------------------------------------- bucket edges
// 4-byte entries (src only): 1 atomic + 1 scattered 4B store per edge,
// no per-edge dinv loads.
__global__ __launch_bounds__(256) void k_bucket(const int* __restrict__ ei,
                                                const int* __restrict__ rowptr,
                                                int* __restrict__ cursor,
                                                int* __restrict__ edsrc) {
    const int r = blockIdx.y;
    const int* src = ei + (size_t)r * 2 * N_EDGES;
    const int* dst = src + N_EDGES;
    const int* rp = rowptr + (size_t)r * (N_PAD + 1);
    int* cur = cursor + (size_t)r * N_NODES;
    int* ed = edsrc + (size_t)r * N_EDGES;
    int e = blockIdx.x * 256 + threadIdx.x;
    if (e < N_EDGES) {
        int s = src[e], d = dst[e];
        int pos = rp[d] + atomicAdd(&cur[d], 1);
        ed[pos] = s;
    }
}

// ---------------------------------------------------------------- GEMM
// Y[n][c] = dinv[n] * (bias[c] + sum_k X[n][k] * W[k][c]); fp32 math, fp16 out.
// Fused BN (se/be) acts on the INPUT dim -> per-relation stride K.
__device__ __forceinline__ float ld_f(const float* p)  { return *p; }
__device__ __forceinline__ float ld_f(const __half* p) { return __half2float(*p); }

template<int K, int C, bool BN, typename TI>
__global__ __launch_bounds__(256) void k_gemm(const TI* __restrict__ Xb,
                                              size_t xStrideR,
                                              const float* __restrict__ Wb,
                                              const float* __restrict__ biasB,
                                              const float* __restrict__ seB,
                                              const float* __restrict__ beB,
                                              const float* __restrict__ dinvB,
                                              __half* __restrict__ Yb,
                                              int nodesPerBlock) {
    const int r = blockIdx.y;
    const TI* X = Xb + (size_t)r * xStrideR;
    const float* W = Wb + (size_t)r * K * C;
    const float* bias = biasB + (size_t)r * C;
    const float* se = BN ? seB + (size_t)r * K : nullptr;   // K-stride!
    const float* be = BN ? beB + (size_t)r * K : nullptr;   // K-stride!
    const float* dinv = dinvB + (size_t)r * N_PAD;
    __half* Y = Yb + (size_t)r * N_NODES * C;

    constexpr int CG = C / 4;
    constexpr int NPASS = 256 / CG;
    constexpr int XP = K + 1;
    __shared__ __align__(16) float Ws[K * C];
    __shared__ float Xs[NPASS * XP];
    const int tid = threadIdx.x;
    for (int i = tid; i < K * C; i += 256) Ws[i] = W[i];
    const int cg = tid % CG;
    const int ln = tid / CG;
    const int c0 = cg * 4;
    const float4 bv = *(const float4*)&bias[c0];
    const int blockStart = blockIdx.x * nodesPerBlock;
    const int passes = nodesPerBlock / NPASS;
    for (int p = 0; p < passes; ++p) {
        const int node0 = blockStart + p * NPASS;
        __syncthreads();
        for (int i = tid; i < NPASS * K; i += 256) {
            int lnn = i / K, k = i % K;
            int n = node0 + lnn;
            float v = 0.0f;
            if (n < N_NODES) {
                v = ld_f(&X[(size_t)n * K + k]);
                if (BN) v = fmaxf(v * se[k] + be[k], 0.0f);
            }
            Xs[lnn * XP + k] = v;
        }
        __syncthreads();
        const int n = node0 + ln;
        float4 acc = bv;
        const float* xrow = &Xs[ln * XP];
        #pragma unroll 8
        for (int k = 0; k < K; ++k) {
            float f = xrow[k];
            float4 w = *(const float4*)&Ws[k * C + c0];
            acc.x += f * w.x;
            acc.y += f * w.y;
            acc.z += f * w.z;
            acc.w += f * w.w;
        }
        if (n < N_NODES) {
            const float dv = dinv[n];       // prescale: Y = hs = h * dinv
            ushort4 sv;
            sv.x = __half_as_ushort(__float2half_rn(acc.x * dv));
            sv.y = __half_as_ushort(__float2half_rn(acc.y * dv));
            sv.z = __half_as_ushort(__float2half_rn(acc.z * dv));
            sv.w = __half_as_ushort(__float2half_rn(acc.w * dv));
            *(ushort4*)&Y[(size_t)n * C + c0] = sv;
        }
    }
}

// ---------------------------------------------------------------- gather-agg
// x[n] = g * dinv[n] * sum_e hs[src_e]  +  (1-g) * hs[n] * rdinv[n]
// Block stages its contiguous 4B edge slice in LDS (4096-edge chunks), then
// clamp-free 8-wide loop: only global traffic is the 8 independent hs-row
// gathers. Fused BN partial stats. TO = fp16 for x1, fp32 for x2.
template<int C, int NPB, typename TO>
__global__ __launch_bounds__(256) void k_gather(const __half* __restrict__ hB,
                                                const int* __restrict__ rowptrB,
                                                const int* __restrict__ edsB,
                                                const float* __restrict__ dinvB,
                                                const float* __restrict__ rdinvB,
                                                const float* __restrict__ gammaP,
                                                TO* __restrict__ XB,
                                                float* __restrict__ bnsumB,
                                                float* __restrict__ bnsqB) {
    const int r = blockIdx.y;
    const __half* h = hB + (size_t)r * N_NODES * C;
    const int* rowptr = rowptrB + (size_t)r * (N_PAD + 1);
    const int* edg = edsB + (size_t)r * N_EDGES;
    const float* dinv  = dinvB  + (size_t)r * N_PAD;
    const float* rdinv = rdinvB + (size_t)r * N_PAD;
    TO* X = XB + (size_t)r * N_NODES * C;
    float* bnsum = bnsumB + (size_t)r * C;
    float* bnsq  = bnsqB  + (size_t)r * C;

    constexpr int WPB = 256 / C;        // row slots per block
    constexpr int RPS = NPB / WPB;      // rows per slot
    constexpr int CH  = 4096;           // LDS edge chunk (16 KB, 4B entries)
    __shared__ int eds[CH];
    __shared__ int rp[NPB + 1];
    __shared__ float red[256];
    const int tid = threadIdx.x;
    const int c = tid % C;
    const int slot = tid / C;
    const float g = gammaP[r];
    const float gi = 1.0f - g;
    const int n0 = blockIdx.x * NPB;
    const __half* hc = h + c;
    if (tid <= NPB) {
        int n = n0 + tid;
        rp[tid] = rowptr[(n <= N_NODES) ? n : N_NODES];
    }
    __syncthreads();
    const int bs = rp[0];
    const int bEnd = rp[NPB];
    int rs[RPS], re[RPS];
    float acc[RPS];
    #pragma unroll
    for (int i = 0; i < RPS; ++i) {
        int ri = slot + i * WPB;
        rs[i] = rp[ri];
        re[i] = rp[ri + 1];
        acc[i] = 0.0f;
    }
    for (int ck = bs; ck < bEnd; ck += CH) {
        const int c1 = min(ck + CH, bEnd);
        const int cnt = c1 - ck;
        __syncthreads();
        for (int j = tid; j < cnt; j += 256) eds[j] = edg[ck + j];
        __syncthreads();
        #pragma unroll
        for (int i = 0; i < RPS; ++i) {
            const int lo = max(rs[i], ck);
            const int hi = min(re[i], c1);
            if (lo >= hi) continue;
            float a = acc[i];
            int e = lo;
            const int efull = lo + ((hi - lo) & ~7);
            for (; e < efull; e += 8) {           // clamp-free main body
                int ed[8];
                #pragma unroll
                for (int j = 0; j < 8; ++j) ed[j] = eds[e - ck + j];
                float v[8];
                #pragma unroll
                for (int j = 0; j < 8; ++j)
                    v[j] = __half2float(hc[(unsigned)ed[j] * C]);
                #pragma unroll
                for (int j = 0; j < 8; ++j) a += v[j];
            }
            if (e < hi) {                         // single clamped tail batch
                int ed[8];
                #pragma unroll
                for (int j = 0; j < 8; ++j) {
                    int t = e + j;
                    ed[j] = eds[((t < hi) ? t : lo) - ck];
                }
                float v[8];
                #pragma unroll
                for (int j = 0; j < 8; ++j)
                    v[j] = __half2float(hc[(unsigned)ed[j] * C]);
                #pragma unroll
                for (int j = 0; j < 8; ++j)
                    a += (e + j < hi) ? v[j] : 0.0f;
            }
            acc[i] = a;
        }
    }
    // finalize: x = g*dinv[n]*acc + (1-g)*hs[n]*rdinv[n]; store + BN stats
    float s = 0.0f, sq = 0.0f;
    #pragma unroll
    for (int i = 0; i < RPS; ++i) {
        int n = n0 + slot + i * WPB;
        if (n < N_NODES) {
            float x = g * dinv[n] * acc[i]
                    + gi * rdinv[n] * __half2float(hc[(unsigned)n * C]);
            if constexpr (sizeof(TO) == 2)
                X[(size_t)n * C + c] = __float2half_rn(x);
            else
                X[(size_t)n * C + c] = x;
            s += x;
            sq += x * x;
        }
    }
    __syncthreads();
    red[tid] = s;
    __syncthreads();
    if (slot == 0) {
        float t = 0.0f;
        #pragma unroll
        for (int i = 0; i < WPB; ++i) t += red[c + i * C];
        atomicAdd(&bnsum[c], t);
    }
    __syncthreads();
    red[tid] = sq;
    __syncthreads();
    if (slot == 0) {
        float t = 0.0f;
        #pragma unroll
        for (int i = 0; i < WPB; ++i) t += red[c + i * C];
        atomicAdd(&bnsq[c], t);
    }
}

// ---------------------------------------------------------------- BN finalize
template<int C>
__global__ void k_bnfin(const float* __restrict__ bnsum,
                        const float* __restrict__ bnsq,
                        const float* __restrict__ scale,
                        const float* __restrict__ bias,
                        float* __restrict__ se, float* __restrict__ be) {
    const int r = blockIdx.x;
    int c = threadIdx.x;
    if (c < C) {
        int i = r * C + c;
        float m = bnsum[i] * (1.0f / N_NODES);
        float v = bnsq[i] * (1.0f / N_NODES) - m * m;
        float inv = rsqrtf(v + BN_EPS);
        float sc = inv * scale[i];
        se[i] = sc;
        be[i] = bias[i] - m * sc;
    }
}

// ---------------------------------------------------------------- output
__global__ __launch_bounds__(256) void k_out(const float* __restrict__ x2B,
                                             const int* __restrict__ batch,
                                             const float* __restrict__ seB,
                                             const float* __restrict__ beB,
                                             float* __restrict__ out) {
    const int r = blockIdx.y;
    const float* x2 = x2B + (size_t)r * N_NODES * 32;
    const float* se = seB + r * 32;
    const float* be = beB + r * 32;
    int gid = blockIdx.x * 256 + threadIdx.x;
    int b = gid >> 5;
    int c = gid & 31;
    if (b < 50000) {
        int node = batch[b];
        float y = fmaxf(x2[(size_t)node * 32 + c] * se[c] + be[c], 0.0f);
        float m = y;
        #pragma unroll
        for (int off = 16; off; off >>= 1) m = fmaxf(m, __shfl_xor(m, off, 32));
        float ex = __expf(y - m);
        float ssum = ex;
        #pragma unroll
        for (int off = 16; off; off >>= 1) ssum += __shfl_xor(ssum, off, 32);
        out[(size_t)b * (N_REL * 32) + r * 32 + c] = (y - m) - __logf(ssum);
    }
}

// ---------------------------------------------------------------- launcher
extern "C" void kernel_launch(void* const* d_in, const int* in_sizes, int n_in,
                              void* d_out, int out_size, void* d_ws, size_t ws_size,
                              hipStream_t stream) {
    const float* features    = (const float*)d_in[0];
    const int*   edge_index  = (const int*)d_in[1];
    const int*   batch_nodes = (const int*)d_in[2];
    const float* W1          = (const float*)d_in[3];
    const float* b1          = (const float*)d_in[4];
    const float* W2          = (const float*)d_in[5];
    const float* b2          = (const float*)d_in[6];
    const float* gamma1      = (const float*)d_in[7];
    const float* gamma2      = (const float*)d_in[8];
    const float* bn1_scale   = (const float*)d_in[9];
    const float* bn1_bias    = (const float*)d_in[10];
    const float* bn2_scale   = (const float*)d_in[11];
    const float* bn2_bias    = (const float*)d_in[12];
    float* out = (float*)d_out;

    // ---- workspace layout (byte offsets, 16B aligned), relation-batched ----
    char* wsB = (char*)d_ws;
    size_t off = 0;
    auto alloc = [&](size_t bytes) {
        void* p = wsB + off;
        off = (off + bytes + 15) & ~(size_t)15;
        return p;
    };
    // zero-region (single memset): deg (padded) + cursor + bn sums, all rel
    int*   deg    = (int*)alloc((size_t)N_REL * N_PAD * 4);
    int*   cursor = (int*)alloc((size_t)N_REL * N_NODES * 4);
    float* bnsum1 = (float*)alloc(N_REL * 64 * 4);
    float* bnsq1  = (float*)alloc(N_REL * 64 * 4);
    float* bnsum2 = (float*)alloc(N_REL * 32 * 4);
    float* bnsq2  = (float*)alloc(N_REL * 32 * 4);
    const size_t zeroBytes = off;
    // non-zeroed scratch
    float* dinv      = (float*)alloc((size_t)N_REL * N_PAD * 4);
    float* rdinv     = (float*)alloc((size_t)N_REL * N_PAD * 4);
    int*   rowptr    = (int*)alloc((size_t)N_REL * (N_PAD + 1) * 4);
    int*   blockSums = (int*)alloc(N_REL * 128 * 4);
    int*   blockOff  = (int*)alloc(N_REL * 128 * 4);
    float* se1 = (float*)alloc(N_REL * 64 * 4);
    float* be1 = (float*)alloc(N_REL * 64 * 4);
    float* se2 = (float*)alloc(N_REL * 32 * 4);
    float* be2 = (float*)alloc(N_REL * 32 * 4);
    int*    edsrc = (int*)alloc((size_t)N_REL * N_EDGES * 4);        // 19.2 MB
    __half* h1   = (__half*)alloc((size_t)N_REL * N_NODES * 64 * 2); // 38.4 MB (hs)
    __half* x1   = (__half*)alloc((size_t)N_REL * N_NODES * 64 * 2); // 19.2 MB
    __half* h2   = (__half*)alloc((size_t)N_REL * N_NODES * 32 * 2); //  9.6 MB (hs)
    float*  x2   = (float*)h1;  // alias: h1 dead after gather64; needs 38.4 MB

    hipMemsetAsync(d_ws, 0, zeroBytes, stream);

    // ---- CSR build (all relations) ----
    k_deg<<<dim3((N_EDGES + 255) / 256, N_REL), 256, 0, stream>>>(edge_index, deg);
    k_blocksum<<<dim3(NSCAN, N_REL), 256, 0, stream>>>(deg, blockSums, dinv, rdinv);
    k_scanoff<<<N_REL, 128, 0, stream>>>(blockSums, blockOff, rowptr);
    k_scan2<<<dim3(NSCAN, N_REL), 256, 0, stream>>>(deg, blockOff, rowptr);
    k_bucket<<<dim3((N_EDGES + 255) / 256, N_REL), 256, 0, stream>>>(
        edge_index, rowptr, cursor, edsrc);

    // ---- conv1 ----
    k_gemm<128, 64, false, float><<<dim3((N_NODES + 63) / 64, N_REL), 256, 0, stream>>>(
        features, 0, W1, b1, nullptr, nullptr, dinv, h1, 64);
    k_gather<64, 32, __half><<<dim3((N_NODES + 31) / 32, N_REL), 256, 0, stream>>>(
        h1, rowptr, edsrc, dinv, rdinv, gamma1, x1, bnsum1, bnsq1);
    k_bnfin<64><<<N_REL, 64, 0, stream>>>(bnsum1, bnsq1, bn1_scale, bn1_bias, se1, be1);

    // ---- conv2 (BN+relu fused into GEMM load) ----
    k_gemm<64, 32, true, __half><<<dim3((N_NODES + 127) / 128, N_REL), 256, 0, stream>>>(
        x1, (size_t)N_NODES * 64, W2, b2, se1, be1, dinv, h2, 128);
    k_gather<32, 64, float><<<dim3((N_NODES + 63) / 64, N_REL), 256, 0, stream>>>(
        h2, rowptr, edsrc, dinv, rdinv, gamma2, x2, bnsum2, bnsq2);
    k_bnfin<32><<<N_REL, 32, 0, stream>>>(bnsum2, bnsq2, bn2_scale, bn2_bias, se2, be2);

    // ---- output ----
    k_out<<<dim3((50000 * 32 + 255) / 256, N_REL), 256, 0, stream>>>(
        x2, batch_nodes, se2, be2, out);
}